// Round 8
// baseline (909.626 us; speedup 1.0000x reference)
//
#include <hip/hip_runtime.h>
#include <hip/hip_bf16.h>

#define NE 800000
#define NN 50000
#define NG 16
#define ETOT (NE + NN)

typedef unsigned short u16;
typedef __attribute__((ext_vector_type(8))) short short8;
typedef __attribute__((ext_vector_type(4))) float float4v;

__device__ __forceinline__ float b2f(u16 u) {
  return __uint_as_float(((unsigned)u) << 16);
}
__device__ __forceinline__ u16 f2b(float f) {
  __hip_bfloat16 b = __float2bfloat16(f);
  return *(u16*)&b;
}
__device__ __forceinline__ void cv8(uint4 v, float* o) {
  o[0] = __uint_as_float(v.x << 16);
  o[1] = __uint_as_float(v.x & 0xFFFF0000u);
  o[2] = __uint_as_float(v.y << 16);
  o[3] = __uint_as_float(v.y & 0xFFFF0000u);
  o[4] = __uint_as_float(v.z << 16);
  o[5] = __uint_as_float(v.z & 0xFFFF0000u);
  o[6] = __uint_as_float(v.w << 16);
  o[7] = __uint_as_float(v.w & 0xFFFF0000u);
}
__device__ __forceinline__ unsigned pk2(float a, float b) {
  return (unsigned)f2b(a) | ((unsigned)f2b(b) << 16);
}
__device__ __forceinline__ unsigned f2key(float f) {
  unsigned u = __float_as_uint(f);
  return (u & 0x80000000u) ? ~u : (u | 0x80000000u);
}
__device__ __forceinline__ float key2f(unsigned k) {
  unsigned u = (k & 0x80000000u) ? (k ^ 0x80000000u) : ~k;
  return __uint_as_float(u);
}

// ================= dtype detector (proven R4) =================
__device__ __forceinline__ int plaus(unsigned h) {
  unsigned eh = (h >> 7) & 0xFF;
  return (h == 0) || (eh >= 100 && eh <= 140);
}
__global__ __launch_bounds__(256) void k_detect(const unsigned* __restrict__ a,
                                                const unsigned* __restrict__ b,
                                                const unsigned* __restrict__ c,
                                                int* __restrict__ flags) {
  __shared__ int cnt[3];
  if (threadIdx.x < 3) cnt[threadIdx.x] = 0;
  __syncthreads();
  const unsigned* arr[3] = {a, b, c};
  for (int k = 0; k < 3; k++) {
    int ok = 0;
    for (int i = threadIdx.x; i < 4096; i += 256) {
      unsigned w = arr[k][i];
      ok += (plaus(w & 0xFFFFu) && plaus(w >> 16)) ? 1 : 0;
    }
    atomicAdd(&cnt[k], ok);
  }
  __syncthreads();
  if (threadIdx.x == 0) {
    int f0 = cnt[0] > 2048, f1 = cnt[1] > 2048, f2 = cnt[2] > 2048;
    flags[0] = f0;
    flags[1] = f1;
    flags[2] = f2;
    flags[3] = f0 && f1 && f2;
  }
}

// ================= edge_attr column sums (self-loop mean row) =================
__global__ __launch_bounds__(256) void k_ea_colsum(const void* __restrict__ ea,
                                                   const int* __restrict__ flg,
                                                   float* __restrict__ sums) {
  bool eb = flg[2] != 0;
  int gt = blockIdx.x * 256 + threadIdx.x;
  int col = gt & 15;
  int row = gt >> 4;
  int rstride = (gridDim.x * 256) >> 4;
  float s = 0.f;
  if (eb) {
    const u16* p = (const u16*)ea;
    for (int e = row; e < NE; e += rstride) s += b2f(p[(size_t)e * 16 + col]);
  } else {
    const float* p = (const float*)ea;
    for (int e = row; e < NE; e += rstride) s += p[(size_t)e * 16 + col];
  }
  __shared__ float ls[256];
  ls[threadIdx.x] = s;
  __syncthreads();
  if (threadIdx.x < 16) {
    float t = 0.f;
    for (int i = threadIdx.x; i < 256; i += 16) t += ls[i];
    atomicAdd(&sums[threadIdx.x], t);
  }
}

// ================= CSR build (once; graph is layer-invariant) =================
__global__ __launch_bounds__(256) void k_hist(const int* __restrict__ ei,
                                              int* __restrict__ deg) {
  int e = blockIdx.x * 256 + threadIdx.x;
  if (e >= ETOT) return;
  int dst = (e < NE) ? ei[NE + e] : e - NE;
  atomicAdd(&deg[dst], 1);
}

__global__ __launch_bounds__(256) void k_scan(const int* __restrict__ deg,
                                              int* __restrict__ start,
                                              int* __restrict__ cursor) {
  __shared__ int ps[256];
  int t = threadIdx.x;
  const int CH = (NN + 255) / 256;
  int b0 = t * CH;
  int bend = min(b0 + CH, NN);
  int s = 0;
  for (int i = b0; i < bend; i++) s += deg[i];
  ps[t] = s;
  __syncthreads();
  for (int ofs = 1; ofs < 256; ofs <<= 1) {
    int v = (t >= ofs) ? ps[t - ofs] : 0;
    __syncthreads();
    ps[t] += v;
    __syncthreads();
  }
  int run = (t == 0) ? 0 : ps[t - 1];
  for (int i = b0; i < bend; i++) {
    start[i] = run;
    cursor[i] = run;
    run += deg[i];
  }
  if (t == 255) start[NN] = run;
}

__global__ __launch_bounds__(256) void k_buildcsr(const int* __restrict__ ei,
                                                  int* __restrict__ cursor,
                                                  uint2* __restrict__ csr) {
  int e = blockIdx.x * 256 + threadIdx.x;
  if (e >= ETOT) return;
  int src, dst;
  if (e < NE) { src = ei[e]; dst = ei[NE + e]; } else { src = dst = e - NE; }
  int pos = atomicAdd(&cursor[dst], 1);
  uint2 r; r.x = (unsigned)src; r.y = (unsigned)e;
  csr[pos] = r;
}

// ==== MFMA 3x linear (bf16 fast path): out(bf16) = x @ W + b ====
// Runs only when weights (and x for XMODE 0) are bf16; else early-exits and
// the VALU fallback below does the work. 50000 rows = 3125 tiles = 125 x 25.
template <int K, int N, int XMODE>
__global__ __launch_bounds__(256) void k_linear3_mfma(
    const void* __restrict__ xin, const int* __restrict__ flg,
    const void* W0, const void* W1, const void* W2,
    const void* b0, const void* b1, const void* b2,
    u16* __restrict__ o0, u16* __restrict__ o1, u16* __restrict__ o2) {
  bool wb = flg[1] != 0;
  bool xb = (XMODE == 1) ? true : (flg[0] != 0);
  if (!(wb && xb)) return;
  constexpr int CT = N / 16;   // col tiles (4 or 2)
  constexpr int WPC = 4 / CT;  // row-tile interleave across waves
  constexpr int KK = K / 32;   // k-steps
  const u16* W = (const u16*)(blockIdx.y == 0 ? W0 : (blockIdx.y == 1 ? W1 : W2));
  const u16* bb = (const u16*)(blockIdx.y == 0 ? b0 : (blockIdx.y == 1 ? b1 : b2));
  u16* out = blockIdx.y == 0 ? o0 : (blockIdx.y == 1 ? o1 : o2);
  const u16* xp = (const u16*)xin;

  __shared__ u16 Wl[K * N];
  for (int i = threadIdx.x; i < K * N / 8; i += 256)
    *(uint4*)&Wl[i * 8] = ((const uint4*)W)[i];
  __syncthreads();

  int wave = threadIdx.x >> 6;
  int lane = threadIdx.x & 63;
  int col = lane & 15;
  int quad = lane >> 4;
  int ct = wave % CT;
  int rt_off = wave / CT;

  // B fragments: B[k=quad*8+j][n=ct*16+col] -> registers, reused all row-tiles
  short8 bfrag[KK];
#pragma unroll
  for (int kk = 0; kk < KK; kk++) {
    short8 t;
#pragma unroll
    for (int j = 0; j < 8; j++)
      t[j] = (short)Wl[(kk * 32 + quad * 8 + j) * N + ct * 16 + col];
    bfrag[kk] = t;
  }
  float bias = b2f(bb[ct * 16 + col]);

  constexpr int RPB = 25;
  int rt0 = blockIdx.x * RPB;
  for (int i = rt_off; i < RPB; i += WPC) {
    int rt = rt0 + i;
    int row = rt * 16 + col;  // A: m = lane&15
    float4v acc = {0.f, 0.f, 0.f, 0.f};
#pragma unroll
    for (int kk = 0; kk < KK; kk++) {
      short8 afrag = *(const short8*)(xp + (size_t)row * K + kk * 32 + quad * 8);
      acc = __builtin_amdgcn_mfma_f32_16x16x32_bf16(afrag, bfrag[kk], acc, 0, 0, 0);
    }
    // C/D: col = lane&15, row_in_tile = quad*4 + r
#pragma unroll
    for (int r = 0; r < 4; r++) {
      int orow = rt * 16 + quad * 4 + r;
      out[(size_t)orow * N + ct * 16 + col] = f2b(acc[r] + bias);
    }
  }
}

// ==== VALU 3x linear (fallback; early-exits on bf16 fast path) ====
template <int K, int N, int XMODE>
__global__ __launch_bounds__(256) void k_linear3(
    const void* __restrict__ xin, const int* __restrict__ flg,
    const void* W0, const void* W1, const void* W2,
    const void* b0, const void* b1, const void* b2,
    u16* __restrict__ o0, u16* __restrict__ o1, u16* __restrict__ o2, int M) {
  bool wb = flg[1] != 0;
  bool xb = (XMODE == 1) ? true : (flg[0] != 0);
  if (wb && xb) return;  // MFMA kernel handled it
  const void* W = blockIdx.y == 0 ? W0 : (blockIdx.y == 1 ? W1 : W2);
  const void* bb = blockIdx.y == 0 ? b0 : (blockIdx.y == 1 ? b1 : b2);
  u16* out = blockIdx.y == 0 ? o0 : (blockIdx.y == 1 ? o1 : o2);

  constexpr int TM = 32;
  constexpr int CPT = (N >= 64) ? 8 : 4;
  constexpr int TCOLS = N / CPT;
  __shared__ __align__(16) float Wf[K * N];
  __shared__ float xs[TM * (K + 1)];
  __shared__ float bfs[N];
  int tid = threadIdx.x;
  if (wb) {
    const u16* Wp = (const u16*)W;
    for (int i = tid; i < K * N / 8; i += 256) {
      float t[8];
      cv8(*(const uint4*)(Wp + i * 8), t);
#pragma unroll
      for (int q = 0; q < 8; q++) Wf[i * 8 + q] = t[q];
    }
  } else {
    const float* Wp = (const float*)W;
    for (int i = tid; i < K * N / 4; i += 256) {
      float4 v = *(const float4*)(Wp + i * 4);
      Wf[i * 4 + 0] = v.x; Wf[i * 4 + 1] = v.y;
      Wf[i * 4 + 2] = v.z; Wf[i * 4 + 3] = v.w;
    }
  }
  if (tid < N) bfs[tid] = wb ? b2f(((const u16*)bb)[tid]) : ((const float*)bb)[tid];
  int r0 = blockIdx.x * TM;
  if (xb) {
    const u16* xp = (const u16*)xin;
    for (int i = tid; i < TM * K / 8; i += 256) {
      int lr = i / (K / 8), lc = (i % (K / 8)) * 8;
      int gr = r0 + lr;
      float t[8] = {0, 0, 0, 0, 0, 0, 0, 0};
      if (gr < M) cv8(*(const uint4*)(xp + (size_t)gr * K + lc), t);
#pragma unroll
      for (int q = 0; q < 8; q++) xs[lr * (K + 1) + lc + q] = t[q];
    }
  } else {
    const float* xp = (const float*)xin;
    for (int i = tid; i < TM * K / 4; i += 256) {
      int lr = i / (K / 4), lc = (i % (K / 4)) * 4;
      int gr = r0 + lr;
      float4 v = {0, 0, 0, 0};
      if (gr < M) v = *(const float4*)(xp + (size_t)gr * K + lc);
      xs[lr * (K + 1) + lc + 0] = v.x;
      xs[lr * (K + 1) + lc + 1] = v.y;
      xs[lr * (K + 1) + lc + 2] = v.z;
      xs[lr * (K + 1) + lc + 3] = v.w;
    }
  }
  __syncthreads();
  int tc = tid % TCOLS, tr = tid / TCOLS;
  float acc[CPT];
#pragma unroll
  for (int c = 0; c < CPT; c++) acc[c] = bfs[tc * CPT + c];
#pragma unroll 4
  for (int k = 0; k < K; k++) {
    float xv = xs[tr * (K + 1) + k];
#pragma unroll
    for (int c = 0; c < CPT; c++) acc[c] += xv * Wf[k * N + tc * CPT + c];
  }
  int gr = r0 + tr;
  if (gr < M) {
    u16* op = out + (size_t)gr * N + tc * CPT;
    if constexpr (CPT == 8) {
      uint4 o;
      o.x = pk2(acc[0], acc[1]); o.y = pk2(acc[2], acc[3]);
      o.z = pk2(acc[4], acc[5]); o.w = pk2(acc[6], acc[7]);
      *(uint4*)op = o;
    } else {
      uint2 o;
      o.x = pk2(acc[0], acc[1]); o.y = pk2(acc[2], acc[3]);
      *(uint2*)op = o;
    }
  }
}

// ===== per-edge ev = eattr[eid] . We[:,ch] =====
__device__ __forceinline__ float edot16(unsigned eid, const void* __restrict__ eattr,
                                        bool eb, const float* Wreg, float ev_self) {
  if (eid >= NE) return ev_self;
  float ea[16];
  if (eb) {
    const uint4* q = (const uint4*)((const u16*)eattr + (size_t)eid * 16);
    cv8(q[0], ea);
    cv8(q[1], ea + 8);
  } else {
    const float* q = (const float*)eattr + (size_t)eid * 16;
#pragma unroll
    for (int k = 0; k < 16; k++) ea[k] = q[k];
  }
  float ev = 0.f;
#pragma unroll
  for (int k = 0; k < 16; k++) ev += ea[k] * Wreg[k];
  return ev;
}

// ===== fused attention + softmax gather-reduce (no-LDS, Wreg, unroll-4) =====
template <int H, int C>
__global__ __launch_bounds__(256) void k_fused(
    const int* __restrict__ start, const uint2* __restrict__ csr,
    const void* __restrict__ eattr, const int* __restrict__ flg,
    const float* __restrict__ mean_sums,
    const u16* __restrict__ xl, const u16* __restrict__ xr,
    const void* We, const void* att, u16* __restrict__ agg) {
  constexpr int D = H * C;
  constexpr int NPW = 64 / D;
  bool wb = flg[1] != 0;
  bool eb = flg[2] != 0;
  int lane = threadIdx.x & 63;
  int ch = lane % D;
  float Wreg[16];
  if (wb) {
    const u16* Wp = (const u16*)We;
#pragma unroll
    for (int k = 0; k < 16; k++) Wreg[k] = b2f(Wp[k * D + ch]);
  } else {
    const float* Wp = (const float*)We;
#pragma unroll
    for (int k = 0; k < 16; k++) Wreg[k] = Wp[k * D + ch];
  }
  float attv = wb ? b2f(((const u16*)att)[ch]) : ((const float*)att)[ch];
  float ev_self = 0.f;
#pragma unroll
  for (int k = 0; k < 16; k++) ev_self += mean_sums[k] * (1.0f / NE) * Wreg[k];

  int wid = (blockIdx.x * 256 + threadIdx.x) >> 6;
  int node = wid * NPW + lane / D;
  if (node >= NN) return;
  int s0 = start[node], s1 = start[node + 1];
  int deg = s1 - s0;
  int degmax = deg;
  if constexpr (NPW == 2) degmax = max(deg, __shfl_xor(deg, 32, 64));
  float xrv = b2f(xr[(size_t)node * D + ch]);
  float ssum = 0.f, acc = 0.f;
  for (int i = 0; i < degmax; i += 4) {
    bool a0 = i < deg, a1 = i + 1 < deg, a2 = i + 2 < deg, a3 = i + 3 < deg;
    int last = s1 - 1;
    int p0 = min(s0 + i, last), p1 = min(s0 + i + 1, last);
    int p2 = min(s0 + i + 2, last), p3 = min(s0 + i + 3, last);
    uint2 cr0 = csr[p0], cr1 = csr[p1], cr2 = csr[p2], cr3 = csr[p3];
    float xlv0 = b2f(xl[(size_t)cr0.x * D + ch]);
    float xlv1 = b2f(xl[(size_t)cr1.x * D + ch]);
    float xlv2 = b2f(xl[(size_t)cr2.x * D + ch]);
    float xlv3 = b2f(xl[(size_t)cr3.x * D + ch]);
    float ev0 = edot16(cr0.y, eattr, eb, Wreg, ev_self);
    float ev1 = edot16(cr1.y, eattr, eb, Wreg, ev_self);
    float ev2 = edot16(cr2.y, eattr, eb, Wreg, ev_self);
    float ev3 = edot16(cr3.y, eattr, eb, Wreg, ev_self);
    float mv0 = xlv0 + xrv + ev0;
    float mv1 = xlv1 + xrv + ev1;
    float mv2 = xlv2 + xrv + ev2;
    float mv3 = xlv3 + xrv + ev3;
    mv0 = (mv0 > 0.f) ? mv0 : 0.2f * mv0;
    mv1 = (mv1 > 0.f) ? mv1 : 0.2f * mv1;
    mv2 = (mv2 > 0.f) ? mv2 : 0.2f * mv2;
    mv3 = (mv3 > 0.f) ? mv3 : 0.2f * mv3;
    float t0 = mv0 * attv, t1 = mv1 * attv, t2 = mv2 * attv, t3 = mv3 * attv;
#pragma unroll
    for (int mk = 1; mk <= 16; mk <<= 1) {
      t0 += __shfl_xor(t0, mk, 64);
      t1 += __shfl_xor(t1, mk, 64);
      t2 += __shfl_xor(t2, mk, 64);
      t3 += __shfl_xor(t3, mk, 64);
    }
    float ex0 = a0 ? __expf(t0) : 0.f;
    float ex1 = a1 ? __expf(t1) : 0.f;
    float ex2 = a2 ? __expf(t2) : 0.f;
    float ex3 = a3 ? __expf(t3) : 0.f;
    ssum += (ex0 + ex1) + (ex2 + ex3);
    acc += (ex0 * xlv0 + ex1 * xlv1) + (ex2 * xlv2 + ex3 * xlv3);
  }
  agg[(size_t)node * D + ch] = f2b(acc / (ssum + 1e-16f));
}

// ================= batch-norm reduce (agg bf16) =================
template <int D>
__global__ __launch_bounds__(256) void k_bnred(const u16* __restrict__ v,
                                               float* __restrict__ sum,
                                               float* __restrict__ sq, int M) {
  constexpr int RB = 256 / D;
  int tid = threadIdx.x;
  int c = tid % D;
  int rg = tid / D;
  float s = 0.f, q = 0.f;
  for (int r = blockIdx.x * RB + rg; r < M; r += gridDim.x * RB) {
    float x = b2f(v[(size_t)r * D + c]);
    s += x;
    q += x * x;
  }
  __shared__ float ls[256], lq[256];
  ls[tid] = s; lq[tid] = q;
  __syncthreads();
  if (tid < D) {
    float ts = 0.f, tq = 0.f;
    for (int i = tid; i < 256; i += D) { ts += ls[i]; tq += lq[i]; }
    atomicAdd(&sum[tid], ts);
    atomicAdd(&sq[tid], tq);
  }
}

// ================= batch-norm apply + skip + ELU =================
template <int D>
__global__ __launch_bounds__(256) void k_bnapply(const u16* __restrict__ agg,
                                                 const u16* __restrict__ hp,
                                                 const float* __restrict__ sum,
                                                 const float* __restrict__ sq,
                                                 const void* g, const void* b,
                                                 const int* __restrict__ flg,
                                                 u16* __restrict__ out, int M) {
  bool wb = flg[1] != 0;
  int idx = blockIdx.x * 256 + threadIdx.x;
  if (idx >= M * D) return;
  int c = idx & (D - 1);
  float gc = wb ? b2f(((const u16*)g)[c]) : ((const float*)g)[c];
  float bc = wb ? b2f(((const u16*)b)[c]) : ((const float*)b)[c];
  float mu = sum[c] * (1.f / M);
  float var = fmaxf(sq[c] * (1.f / M) - mu * mu, 0.f);
  float sc = rsqrtf(var + 1e-5f) * gc;
  float v = (b2f(agg[idx]) - mu) * sc + bc + b2f(hp[idx]);
  v = v > 0.f ? v : expm1f(v);
  out[idx] = f2b(v);
}

// ================= graph pooling =================
__global__ __launch_bounds__(256) void k_pool(const u16* __restrict__ h2,
                                              const int* __restrict__ batch,
                                              float* __restrict__ pool_sum,
                                              unsigned* __restrict__ pool_maxk,
                                              float* __restrict__ pool_cnt, int M) {
  const int NPB = 2048;
  int c = threadIdx.x & 31;
  int rg = threadIdx.x >> 5;
  int n0 = blockIdx.x * NPB;
  int nend = min(n0 + NPB, M);
  int cur = -1;
  float s = 0.f, mx = 0.f;
  int cnt = 0;
  for (int n = n0 + rg; n < nend; n += 8) {
    int g = batch[n];
    float v = b2f(h2[(size_t)n * 32 + c]);
    if (g != cur) {
      if (cur >= 0) {
        atomicAdd(&pool_sum[cur * 32 + c], s);
        atomicMax(&pool_maxk[cur * 32 + c], f2key(mx));
        if (c == 0) atomicAdd(&pool_cnt[cur], (float)cnt);
      }
      cur = g; s = 0.f; mx = -INFINITY; cnt = 0;
    }
    s += v;
    mx = fmaxf(mx, v);
    cnt++;
  }
  if (cur >= 0) {
    atomicAdd(&pool_sum[cur * 32 + c], s);
    atomicMax(&pool_maxk[cur * 32 + c], f2key(mx));
    if (c == 0) atomicAdd(&pool_cnt[cur], (float)cnt);
  }
}

__global__ __launch_bounds__(256) void k_poolfinal(const float* __restrict__ pool_sum,
                                                   const unsigned* __restrict__ pool_maxk,
                                                   const float* __restrict__ pool_cnt,
                                                   const int* __restrict__ flg,
                                                   void* __restrict__ out) {
  bool ob = flg[3] != 0;
  int idx = blockIdx.x * 256 + threadIdx.x;
  if (idx >= NG * 64) return;
  int g = idx / 64, c = idx % 64;
  float cnt = pool_cnt[g];
  float val;
  if (c < 32) val = pool_sum[g * 32 + c] / fmaxf(cnt, 1.f);
  else val = cnt > 0.f ? key2f(pool_maxk[g * 32 + (c - 32)]) : 0.f;
  if (ob) ((u16*)out)[idx] = f2b(val);
  else ((float*)out)[idx] = val;
}

extern "C" void kernel_launch(void* const* d_in, const int* in_sizes, int n_in,
                              void* d_out, int out_size, void* d_ws, size_t ws_size,
                              hipStream_t stream) {
  (void)in_sizes; (void)n_in; (void)out_size; (void)ws_size;
  const void* x     = d_in[0];
  const int*  ei    = (const int*)d_in[1];
  const void* eattr = d_in[2];
  const int*  batch = (const int*)d_in[3];
  const void* skip1_W = d_in[4];
  const void* skip1_b = d_in[5];
  const void* c1_Wl = d_in[6];
  const void* c1_bl = d_in[7];
  const void* c1_Wr = d_in[8];
  const void* c1_br = d_in[9];
  const void* c1_We = d_in[10];
  const void* c1_att = d_in[11];
  const void* bn1_g = d_in[13];
  const void* bn1_b = d_in[14];
  const void* skip2_W = d_in[15];
  const void* skip2_b = d_in[16];
  const void* c2_Wl = d_in[17];
  const void* c2_bl = d_in[18];
  const void* c2_Wr = d_in[19];
  const void* c2_br = d_in[20];
  const void* c2_We = d_in[21];
  const void* c2_att = d_in[22];
  const void* bn2_g = d_in[24];
  const void* bn2_b = d_in[25];

  float* ws = (float*)d_ws;
  size_t off = 0;
  auto alloc = [&](size_t nfl) {
    float* p = ws + off;
    off += (nfl + 15) & ~(size_t)15;
    return p;
  };
  // ---- zero-initialized region (memset) ----
  int*   flags      = (int*)alloc(16);
  float* mean_sums  = alloc(16);
  int*   deg        = (int*)alloc(NN);
  float* bnsum1     = alloc(64);
  float* bnsq1      = alloc(64);
  float* bnsum2     = alloc(32);
  float* bnsq2      = alloc(32);
  float* pool_cnt   = alloc(NG);
  float* pool_sum   = alloc(NG * 32);
  unsigned* pool_maxk = (unsigned*)alloc(NG * 32);
  size_t zbytes = off * sizeof(float);
  // ---- plain scratch (fully written before read) ----
  int* start   = (int*)alloc(NN + 1);
  int* cursor  = (int*)alloc(NN);
  uint2* csr   = (uint2*)alloc((size_t)ETOT * 2);   // {src, eid} per CSR slot
  u16* xl1 = (u16*)alloc((size_t)NN * 32);  // NN*64 bf16
  u16* xr1 = (u16*)alloc((size_t)NN * 32);  // NN*64 bf16; h1 overlays after fused L1
  u16* hp1 = (u16*)alloc((size_t)NN * 32);  // NN*64 bf16; hp2/h2 overlay halves
  u16* agg = (u16*)alloc((size_t)NN * 32);  // NN*64 bf16 (L1); L2 uses first half
  // layer-2 overlays (source regions dead by then)
  u16* h1  = xr1;
  u16* xl2 = xl1;
  u16* xr2 = xl1 + (size_t)NN * 32;
  u16* hp2 = hp1;
  u16* h2  = hp1 + (size_t)NN * 32;
  // total ws: ~33 MB

  hipMemsetAsync(d_ws, 0, zbytes, stream);
  k_detect<<<1, 256, 0, stream>>>((const unsigned*)x, (const unsigned*)skip1_W,
                                  (const unsigned*)eattr, flags);
  k_ea_colsum<<<128, 256, 0, stream>>>(eattr, flags, mean_sums);

  // CSR build once (graph identical for both layers)
  int eg = (ETOT + 255) / 256;
  k_hist<<<eg, 256, 0, stream>>>(ei, deg);
  k_scan<<<1, 256, 0, stream>>>(deg, start, cursor);
  k_buildcsr<<<eg, 256, 0, stream>>>(ei, cursor, csr);

  // ---- layer 1 ----
  {
    dim3 gm(125, 3);
    k_linear3_mfma<128, 64, 0><<<gm, 256, 0, stream>>>(x, flags, c1_Wl, c1_Wr, skip1_W,
                                                       c1_bl, c1_br, skip1_b,
                                                       xl1, xr1, hp1);
    dim3 g((NN + 31) / 32, 3);
    k_linear3<128, 64, 0><<<g, 256, 0, stream>>>(x, flags, c1_Wl, c1_Wr, skip1_W,
                                                 c1_bl, c1_br, skip1_b,
                                                 xl1, xr1, hp1, NN);
  }
  k_fused<2, 32><<<NN / 4, 256, 0, stream>>>(start, csr, eattr, flags, mean_sums,
                                             xl1, xr1, c1_We, c1_att, agg);
  k_bnred<64><<<256, 256, 0, stream>>>(agg, bnsum1, bnsq1, NN);
  k_bnapply<64><<<(NN * 64 + 255) / 256, 256, 0, stream>>>(agg, hp1, bnsum1, bnsq1,
                                                           bn1_g, bn1_b, flags, h1, NN);

  // ---- layer 2 ----
  {
    dim3 gm(125, 3);
    k_linear3_mfma<64, 32, 1><<<gm, 256, 0, stream>>>(h1, flags, c2_Wl, c2_Wr, skip2_W,
                                                      c2_bl, c2_br, skip2_b,
                                                      xl2, xr2, hp2);
    dim3 g((NN + 31) / 32, 3);
    k_linear3<64, 32, 1><<<g, 256, 0, stream>>>(h1, flags, c2_Wl, c2_Wr, skip2_W,
                                                c2_bl, c2_br, skip2_b,
                                                xl2, xr2, hp2, NN);
  }
  k_fused<1, 32><<<NN / 8, 256, 0, stream>>>(start, csr, eattr, flags, mean_sums,
                                             xl2, xr2, c2_We, c2_att, agg);
  k_bnred<32><<<256, 256, 0, stream>>>(agg, bnsum2, bnsq2, NN);
  k_bnapply<32><<<(NN * 32 + 255) / 256, 256, 0, stream>>>(agg, hp2, bnsum2, bnsq2,
                                                           bn2_g, bn2_b, flags, h2, NN);

  k_pool<<<(NN + 2047) / 2048, 256, 0, stream>>>(h2, batch, pool_sum, pool_maxk, pool_cnt, NN);
  k_poolfinal<<<4, 256, 0, stream>>>(pool_sum, pool_maxk, pool_cnt, flags, d_out);
}

// Round 9
// 805.756 us; speedup vs baseline: 1.1289x; 1.1289x over previous
//
#include <hip/hip_runtime.h>
#include <hip/hip_bf16.h>

#define NE 800000
#define NN 50000
#define NG 16
#define ETOT (NE + NN)

typedef unsigned short u16;
typedef __attribute__((ext_vector_type(8))) short short8;
typedef __attribute__((ext_vector_type(4))) float float4v;

__device__ __forceinline__ float b2f(u16 u) {
  return __uint_as_float(((unsigned)u) << 16);
}
__device__ __forceinline__ u16 f2b(float f) {
  __hip_bfloat16 b = __float2bfloat16(f);
  return *(u16*)&b;
}
__device__ __forceinline__ void cv8(uint4 v, float* o) {
  o[0] = __uint_as_float(v.x << 16);
  o[1] = __uint_as_float(v.x & 0xFFFF0000u);
  o[2] = __uint_as_float(v.y << 16);
  o[3] = __uint_as_float(v.y & 0xFFFF0000u);
  o[4] = __uint_as_float(v.z << 16);
  o[5] = __uint_as_float(v.z & 0xFFFF0000u);
  o[6] = __uint_as_float(v.w << 16);
  o[7] = __uint_as_float(v.w & 0xFFFF0000u);
}
__device__ __forceinline__ unsigned pk2(float a, float b) {
  return (unsigned)f2b(a) | ((unsigned)f2b(b) << 16);
}
__device__ __forceinline__ unsigned f2key(float f) {
  unsigned u = __float_as_uint(f);
  return (u & 0x80000000u) ? ~u : (u | 0x80000000u);
}
__device__ __forceinline__ float key2f(unsigned k) {
  unsigned u = (k & 0x80000000u) ? (k ^ 0x80000000u) : ~k;
  return __uint_as_float(u);
}

// ================= dtype detector (proven R4) =================
__device__ __forceinline__ int plaus(unsigned h) {
  unsigned eh = (h >> 7) & 0xFF;
  return (h == 0) || (eh >= 100 && eh <= 140);
}
__global__ __launch_bounds__(256) void k_detect(const unsigned* __restrict__ a,
                                                const unsigned* __restrict__ b,
                                                const unsigned* __restrict__ c,
                                                int* __restrict__ flags) {
  __shared__ int cnt[3];
  if (threadIdx.x < 3) cnt[threadIdx.x] = 0;
  __syncthreads();
  const unsigned* arr[3] = {a, b, c};
  for (int k = 0; k < 3; k++) {
    int ok = 0;
    for (int i = threadIdx.x; i < 4096; i += 256) {
      unsigned w = arr[k][i];
      ok += (plaus(w & 0xFFFFu) && plaus(w >> 16)) ? 1 : 0;
    }
    atomicAdd(&cnt[k], ok);
  }
  __syncthreads();
  if (threadIdx.x == 0) {
    int f0 = cnt[0] > 2048, f1 = cnt[1] > 2048, f2 = cnt[2] > 2048;
    flags[0] = f0;
    flags[1] = f1;
    flags[2] = f2;
    flags[3] = f0 && f1 && f2;
  }
}

// ============ merged: dst-degree histogram + edge_attr column sums ============
__global__ __launch_bounds__(256) void k_histcol(const int* __restrict__ ei,
                                                 const void* __restrict__ ea,
                                                 const int* __restrict__ flg,
                                                 int* __restrict__ deg,
                                                 float* __restrict__ sums) {
  int gt = blockIdx.x * 256 + threadIdx.x;
  if (gt < ETOT) {
    int dst = (gt < NE) ? ei[NE + gt] : gt - NE;
    atomicAdd(&deg[dst], 1);
  }
  // colsum over full grid
  bool eb = flg[2] != 0;
  int col = gt & 15;
  int row = gt >> 4;
  int rstride = (gridDim.x * 256) >> 4;
  float s = 0.f;
  if (eb) {
    const u16* p = (const u16*)ea;
    for (int e = row; e < NE; e += rstride) s += b2f(p[(size_t)e * 16 + col]);
  } else {
    const float* p = (const float*)ea;
    for (int e = row; e < NE; e += rstride) s += p[(size_t)e * 16 + col];
  }
  __shared__ float ls[256];
  ls[threadIdx.x] = s;
  __syncthreads();
  if (threadIdx.x < 16) {
    float t = 0.f;
    for (int i = threadIdx.x; i < 256; i += 16) t += ls[i];
    atomicAdd(&sums[threadIdx.x], t);
  }
}

__global__ __launch_bounds__(256) void k_scan(const int* __restrict__ deg,
                                              int* __restrict__ start,
                                              int* __restrict__ cursor) {
  __shared__ int ps[256];
  int t = threadIdx.x;
  const int CH = (NN + 255) / 256;
  int b0 = t * CH;
  int bend = min(b0 + CH, NN);
  int s = 0;
  for (int i = b0; i < bend; i++) s += deg[i];
  ps[t] = s;
  __syncthreads();
  for (int ofs = 1; ofs < 256; ofs <<= 1) {
    int v = (t >= ofs) ? ps[t - ofs] : 0;
    __syncthreads();
    ps[t] += v;
    __syncthreads();
  }
  int run = (t == 0) ? 0 : ps[t - 1];
  for (int i = b0; i < bend; i++) {
    start[i] = run;
    cursor[i] = run;
    run += deg[i];
  }
  if (t == 255) start[NN] = run;
}

__global__ __launch_bounds__(256) void k_buildcsr(const int* __restrict__ ei,
                                                  int* __restrict__ cursor,
                                                  uint2* __restrict__ csr) {
  int e = blockIdx.x * 256 + threadIdx.x;
  if (e >= ETOT) return;
  int src, dst;
  if (e < NE) { src = ei[e]; dst = ei[NE + e]; } else { src = dst = e - NE; }
  int pos = atomicAdd(&cursor[dst], 1);
  uint2 r; r.x = (unsigned)src; r.y = (unsigned)e;
  csr[pos] = r;
}

// ==== MFMA 3x linear (bf16 fast path) ====
template <int K, int N, int XMODE>
__global__ __launch_bounds__(256) void k_linear3_mfma(
    const void* __restrict__ xin, const int* __restrict__ flg,
    const void* W0, const void* W1, const void* W2,
    const void* b0, const void* b1, const void* b2,
    u16* __restrict__ o0, u16* __restrict__ o1, u16* __restrict__ o2) {
  bool wb = flg[1] != 0;
  bool xb = (XMODE == 1) ? true : (flg[0] != 0);
  if (!(wb && xb)) return;
  constexpr int CT = N / 16;
  constexpr int WPC = 4 / CT;
  constexpr int KK = K / 32;
  const u16* W = (const u16*)(blockIdx.y == 0 ? W0 : (blockIdx.y == 1 ? W1 : W2));
  const u16* bb = (const u16*)(blockIdx.y == 0 ? b0 : (blockIdx.y == 1 ? b1 : b2));
  u16* out = blockIdx.y == 0 ? o0 : (blockIdx.y == 1 ? o1 : o2);
  const u16* xp = (const u16*)xin;

  __shared__ u16 Wl[K * N];
  for (int i = threadIdx.x; i < K * N / 8; i += 256)
    *(uint4*)&Wl[i * 8] = ((const uint4*)W)[i];
  __syncthreads();

  int wave = threadIdx.x >> 6;
  int lane = threadIdx.x & 63;
  int col = lane & 15;
  int quad = lane >> 4;
  int ct = wave % CT;
  int rt_off = wave / CT;

  short8 bfrag[KK];
#pragma unroll
  for (int kk = 0; kk < KK; kk++) {
    short8 t;
#pragma unroll
    for (int j = 0; j < 8; j++)
      t[j] = (short)Wl[(kk * 32 + quad * 8 + j) * N + ct * 16 + col];
    bfrag[kk] = t;
  }
  float bias = b2f(bb[ct * 16 + col]);

  constexpr int RPB = 25;
  int rt0 = blockIdx.x * RPB;
  for (int i = rt_off; i < RPB; i += WPC) {
    int rt = rt0 + i;
    int row = rt * 16 + col;
    float4v acc = {0.f, 0.f, 0.f, 0.f};
#pragma unroll
    for (int kk = 0; kk < KK; kk++) {
      short8 afrag = *(const short8*)(xp + (size_t)row * K + kk * 32 + quad * 8);
      acc = __builtin_amdgcn_mfma_f32_16x16x32_bf16(afrag, bfrag[kk], acc, 0, 0, 0);
    }
#pragma unroll
    for (int r = 0; r < 4; r++) {
      int orow = rt * 16 + quad * 4 + r;
      out[(size_t)orow * N + ct * 16 + col] = f2b(acc[r] + bias);
    }
  }
}

// ==== VALU 3x linear (fallback; early-exits on bf16 fast path) ====
template <int K, int N, int XMODE>
__global__ __launch_bounds__(256) void k_linear3(
    const void* __restrict__ xin, const int* __restrict__ flg,
    const void* W0, const void* W1, const void* W2,
    const void* b0, const void* b1, const void* b2,
    u16* __restrict__ o0, u16* __restrict__ o1, u16* __restrict__ o2, int M) {
  bool wb = flg[1] != 0;
  bool xb = (XMODE == 1) ? true : (flg[0] != 0);
  if (wb && xb) return;
  const void* W = blockIdx.y == 0 ? W0 : (blockIdx.y == 1 ? W1 : W2);
  const void* bb = blockIdx.y == 0 ? b0 : (blockIdx.y == 1 ? b1 : b2);
  u16* out = blockIdx.y == 0 ? o0 : (blockIdx.y == 1 ? o1 : o2);

  constexpr int TM = 32;
  constexpr int CPT = (N >= 64) ? 8 : 4;
  constexpr int TCOLS = N / CPT;
  __shared__ __align__(16) float Wf[K * N];
  __shared__ float xs[TM * (K + 1)];
  __shared__ float bfs[N];
  int tid = threadIdx.x;
  if (wb) {
    const u16* Wp = (const u16*)W;
    for (int i = tid; i < K * N / 8; i += 256) {
      float t[8];
      cv8(*(const uint4*)(Wp + i * 8), t);
#pragma unroll
      for (int q = 0; q < 8; q++) Wf[i * 8 + q] = t[q];
    }
  } else {
    const float* Wp = (const float*)W;
    for (int i = tid; i < K * N / 4; i += 256) {
      float4 v = *(const float4*)(Wp + i * 4);
      Wf[i * 4 + 0] = v.x; Wf[i * 4 + 1] = v.y;
      Wf[i * 4 + 2] = v.z; Wf[i * 4 + 3] = v.w;
    }
  }
  if (tid < N) bfs[tid] = wb ? b2f(((const u16*)bb)[tid]) : ((const float*)bb)[tid];
  int r0 = blockIdx.x * TM;
  if (xb) {
    const u16* xp = (const u16*)xin;
    for (int i = tid; i < TM * K / 8; i += 256) {
      int lr = i / (K / 8), lc = (i % (K / 8)) * 8;
      int gr = r0 + lr;
      float t[8] = {0, 0, 0, 0, 0, 0, 0, 0};
      if (gr < M) cv8(*(const uint4*)(xp + (size_t)gr * K + lc), t);
#pragma unroll
      for (int q = 0; q < 8; q++) xs[lr * (K + 1) + lc + q] = t[q];
    }
  } else {
    const float* xp = (const float*)xin;
    for (int i = tid; i < TM * K / 4; i += 256) {
      int lr = i / (K / 4), lc = (i % (K / 4)) * 4;
      int gr = r0 + lr;
      float4 v = {0, 0, 0, 0};
      if (gr < M) v = *(const float4*)(xp + (size_t)gr * K + lc);
      xs[lr * (K + 1) + lc + 0] = v.x;
      xs[lr * (K + 1) + lc + 1] = v.y;
      xs[lr * (K + 1) + lc + 2] = v.z;
      xs[lr * (K + 1) + lc + 3] = v.w;
    }
  }
  __syncthreads();
  int tc = tid % TCOLS, tr = tid / TCOLS;
  float acc[CPT];
#pragma unroll
  for (int c = 0; c < CPT; c++) acc[c] = bfs[tc * CPT + c];
#pragma unroll 4
  for (int k = 0; k < K; k++) {
    float xv = xs[tr * (K + 1) + k];
#pragma unroll
    for (int c = 0; c < CPT; c++) acc[c] += xv * Wf[k * N + tc * CPT + c];
  }
  int gr = r0 + tr;
  if (gr < M) {
    u16* op = out + (size_t)gr * N + tc * CPT;
    if constexpr (CPT == 8) {
      uint4 o;
      o.x = pk2(acc[0], acc[1]); o.y = pk2(acc[2], acc[3]);
      o.z = pk2(acc[4], acc[5]); o.w = pk2(acc[6], acc[7]);
      *(uint4*)op = o;
    } else {
      uint2 o;
      o.x = pk2(acc[0], acc[1]); o.y = pk2(acc[2], acc[3]);
      *(uint2*)op = o;
    }
  }
}

// ===== per-edge ev = eattr[eid] . We[:,ch] =====
__device__ __forceinline__ float edot16(unsigned eid, const void* __restrict__ eattr,
                                        bool eb, const float* Wreg, float ev_self) {
  if (eid >= NE) return ev_self;
  float ea[16];
  if (eb) {
    const uint4* q = (const uint4*)((const u16*)eattr + (size_t)eid * 16);
    cv8(q[0], ea);
    cv8(q[1], ea + 8);
  } else {
    const float* q = (const float*)eattr + (size_t)eid * 16;
#pragma unroll
    for (int k = 0; k < 16; k++) ea[k] = q[k];
  }
  float ev = 0.f;
#pragma unroll
  for (int k = 0; k < 16; k++) ev += ea[k] * Wreg[k];
  return ev;
}

// ===== fused attention + softmax gather-reduce (unroll-2, csr prefetch) =====
template <int H, int C>
__global__ __launch_bounds__(256) void k_fused(
    const int* __restrict__ start, const uint2* __restrict__ csr,
    const void* __restrict__ eattr, const int* __restrict__ flg,
    const float* __restrict__ mean_sums,
    const u16* __restrict__ xl, const u16* __restrict__ xr,
    const void* We, const void* att, u16* __restrict__ agg) {
  constexpr int D = H * C;
  constexpr int NPW = 64 / D;
  bool wb = flg[1] != 0;
  bool eb = flg[2] != 0;
  int lane = threadIdx.x & 63;
  int ch = lane % D;
  float Wreg[16];
  if (wb) {
    const u16* Wp = (const u16*)We;
#pragma unroll
    for (int k = 0; k < 16; k++) Wreg[k] = b2f(Wp[k * D + ch]);
  } else {
    const float* Wp = (const float*)We;
#pragma unroll
    for (int k = 0; k < 16; k++) Wreg[k] = Wp[k * D + ch];
  }
  float attv = wb ? b2f(((const u16*)att)[ch]) : ((const float*)att)[ch];
  float ev_self = 0.f;
#pragma unroll
  for (int k = 0; k < 16; k++) ev_self += mean_sums[k] * (1.0f / NE) * Wreg[k];

  int wid = (blockIdx.x * 256 + threadIdx.x) >> 6;
  int node = wid * NPW + lane / D;
  if (node >= NN) return;
  int s0 = start[node], s1 = start[node + 1];
  int deg = s1 - s0;
  int last = s1 - 1;
  int degmax = deg;
  if constexpr (NPW == 2) degmax = max(deg, __shfl_xor(deg, 32, 64));
  float xrv = b2f(xr[(size_t)node * D + ch]);
  float ssum = 0.f, acc = 0.f;
  // software pipeline: csr entries for iteration i are loaded at i-2
  uint2 nA = csr[s0];
  uint2 nB = csr[min(s0 + 1, last)];
  for (int i = 0; i < degmax; i += 2) {
    uint2 cr0 = nA, cr1 = nB;
    int q0 = min(s0 + i + 2, last);
    int q1 = min(s0 + i + 3, last);
    nA = csr[q0];
    nB = csr[q1];
    bool a0 = i < deg, a1 = i + 1 < deg;
    float xlv0 = b2f(xl[(size_t)cr0.x * D + ch]);
    float xlv1 = b2f(xl[(size_t)cr1.x * D + ch]);
    float ev0 = edot16(cr0.y, eattr, eb, Wreg, ev_self);
    float ev1 = edot16(cr1.y, eattr, eb, Wreg, ev_self);
    float mv0 = xlv0 + xrv + ev0;
    float mv1 = xlv1 + xrv + ev1;
    mv0 = (mv0 > 0.f) ? mv0 : 0.2f * mv0;
    mv1 = (mv1 > 0.f) ? mv1 : 0.2f * mv1;
    float t0 = mv0 * attv, t1 = mv1 * attv;
#pragma unroll
    for (int mk = 1; mk <= 16; mk <<= 1) {
      t0 += __shfl_xor(t0, mk, 64);
      t1 += __shfl_xor(t1, mk, 64);
    }
    float ex0 = a0 ? __expf(t0) : 0.f;
    float ex1 = a1 ? __expf(t1) : 0.f;
    ssum += ex0 + ex1;
    acc += ex0 * xlv0 + ex1 * xlv1;
  }
  agg[(size_t)node * D + ch] = f2b(acc / (ssum + 1e-16f));
}

// ================= batch-norm reduce (agg bf16) =================
template <int D>
__global__ __launch_bounds__(256) void k_bnred(const u16* __restrict__ v,
                                               float* __restrict__ sum,
                                               float* __restrict__ sq, int M) {
  constexpr int RB = 256 / D;
  int tid = threadIdx.x;
  int c = tid % D;
  int rg = tid / D;
  float s = 0.f, q = 0.f;
  for (int r = blockIdx.x * RB + rg; r < M; r += gridDim.x * RB) {
    float x = b2f(v[(size_t)r * D + c]);
    s += x;
    q += x * x;
  }
  __shared__ float ls[256], lq[256];
  ls[tid] = s; lq[tid] = q;
  __syncthreads();
  if (tid < D) {
    float ts = 0.f, tq = 0.f;
    for (int i = tid; i < 256; i += D) { ts += ls[i]; lq[i] = lq[i]; tq += lq[i]; }
    atomicAdd(&sum[tid], ts);
    atomicAdd(&sq[tid], tq);
  }
}

// ================= batch-norm apply + skip + ELU (layer 1 only) =================
template <int D>
__global__ __launch_bounds__(256) void k_bnapply(const u16* __restrict__ agg,
                                                 const u16* __restrict__ hp,
                                                 const float* __restrict__ sum,
                                                 const float* __restrict__ sq,
                                                 const void* g, const void* b,
                                                 const int* __restrict__ flg,
                                                 u16* __restrict__ out, int M) {
  bool wb = flg[1] != 0;
  int idx = blockIdx.x * 256 + threadIdx.x;
  if (idx >= M * D) return;
  int c = idx & (D - 1);
  float gc = wb ? b2f(((const u16*)g)[c]) : ((const float*)g)[c];
  float bc = wb ? b2f(((const u16*)b)[c]) : ((const float*)b)[c];
  float mu = sum[c] * (1.f / M);
  float var = fmaxf(sq[c] * (1.f / M) - mu * mu, 0.f);
  float sc = rsqrtf(var + 1e-5f) * gc;
  float v = (b2f(agg[idx]) - mu) * sc + bc + b2f(hp[idx]);
  v = v > 0.f ? v : expm1f(v);
  out[idx] = f2b(v);
}

// ==== fused: BN2-apply + ELU + graph pool + (last block) finalize ====
__global__ __launch_bounds__(256) void k_poolall(
    const u16* __restrict__ agg2, const u16* __restrict__ hp2,
    const float* __restrict__ sum, const float* __restrict__ sq,
    const void* g, const void* b, const int* __restrict__ flg,
    const int* __restrict__ batch,
    float* __restrict__ pool_sum, unsigned* __restrict__ pool_maxk,
    float* __restrict__ pool_cnt, int* __restrict__ done_cnt,
    void* __restrict__ out) {
  bool wb = flg[1] != 0;
  int c = threadIdx.x & 31;
  int rg = threadIdx.x >> 5;
  float gc = wb ? b2f(((const u16*)g)[c]) : ((const float*)g)[c];
  float bc = wb ? b2f(((const u16*)b)[c]) : ((const float*)b)[c];
  float mu = sum[c] * (1.f / NN);
  float var = fmaxf(sq[c] * (1.f / NN) - mu * mu, 0.f);
  float scl = rsqrtf(var + 1e-5f) * gc;
  float sh = bc - mu * scl;

  const int NPB = 256;
  int n0 = blockIdx.x * NPB;
  int nend = min(n0 + NPB, NN);
  int cur = -1;
  float s = 0.f, mx = 0.f;
  int cnt = 0;
  for (int n = n0 + rg; n < nend; n += 8) {
    int gi = batch[n];
    float v = b2f(agg2[(size_t)n * 32 + c]) * scl + sh + b2f(hp2[(size_t)n * 32 + c]);
    v = v > 0.f ? v : expm1f(v);
    if (gi != cur) {
      if (cur >= 0) {
        atomicAdd(&pool_sum[cur * 32 + c], s);
        atomicMax(&pool_maxk[cur * 32 + c], f2key(mx));
        if (c == 0) atomicAdd(&pool_cnt[cur], (float)cnt);
      }
      cur = gi; s = 0.f; mx = -INFINITY; cnt = 0;
    }
    s += v;
    mx = fmaxf(mx, v);
    cnt++;
  }
  if (cur >= 0) {
    atomicAdd(&pool_sum[cur * 32 + c], s);
    atomicMax(&pool_maxk[cur * 32 + c], f2key(mx));
    if (c == 0) atomicAdd(&pool_cnt[cur], (float)cnt);
  }
  // last finished block finalizes (atomic reads for device-scope visibility)
  __threadfence();
  __syncthreads();
  __shared__ int lastblk;
  if (threadIdx.x == 0) lastblk = (atomicAdd(done_cnt, 1) == (int)gridDim.x - 1);
  __syncthreads();
  if (!lastblk) return;
  bool ob = flg[3] != 0;
  for (int idx = threadIdx.x; idx < NG * 64; idx += 256) {
    int gi = idx / 64, cc = idx % 64;
    float cntv = atomicAdd(&pool_cnt[gi], 0.f);
    float val;
    if (cc < 32) val = atomicAdd(&pool_sum[gi * 32 + cc], 0.f) / fmaxf(cntv, 1.f);
    else {
      unsigned k = atomicMax(&pool_maxk[gi * 32 + (cc - 32)], 0u);
      val = cntv > 0.f ? key2f(k) : 0.f;
    }
    if (ob) ((u16*)out)[idx] = f2b(val);
    else ((float*)out)[idx] = val;
  }
}

extern "C" void kernel_launch(void* const* d_in, const int* in_sizes, int n_in,
                              void* d_out, int out_size, void* d_ws, size_t ws_size,
                              hipStream_t stream) {
  (void)in_sizes; (void)n_in; (void)out_size; (void)ws_size;
  const void* x     = d_in[0];
  const int*  ei    = (const int*)d_in[1];
  const void* eattr = d_in[2];
  const int*  batch = (const int*)d_in[3];
  const void* skip1_W = d_in[4];
  const void* skip1_b = d_in[5];
  const void* c1_Wl = d_in[6];
  const void* c1_bl = d_in[7];
  const void* c1_Wr = d_in[8];
  const void* c1_br = d_in[9];
  const void* c1_We = d_in[10];
  const void* c1_att = d_in[11];
  const void* bn1_g = d_in[13];
  const void* bn1_b = d_in[14];
  const void* skip2_W = d_in[15];
  const void* skip2_b = d_in[16];
  const void* c2_Wl = d_in[17];
  const void* c2_bl = d_in[18];
  const void* c2_Wr = d_in[19];
  const void* c2_br = d_in[20];
  const void* c2_We = d_in[21];
  const void* c2_att = d_in[22];
  const void* bn2_g = d_in[24];
  const void* bn2_b = d_in[25];

  float* ws = (float*)d_ws;
  size_t off = 0;
  auto alloc = [&](size_t nfl) {
    float* p = ws + off;
    off += (nfl + 15) & ~(size_t)15;
    return p;
  };
  // ---- zero-initialized region (memset) ----
  int*   flags      = (int*)alloc(16);
  float* mean_sums  = alloc(16);
  int*   deg        = (int*)alloc(NN);
  float* bnsum1     = alloc(64);
  float* bnsq1      = alloc(64);
  float* bnsum2     = alloc(32);
  float* bnsq2      = alloc(32);
  float* pool_cnt   = alloc(NG);
  float* pool_sum   = alloc(NG * 32);
  unsigned* pool_maxk = (unsigned*)alloc(NG * 32);
  int*   done_cnt   = (int*)alloc(16);
  size_t zbytes = off * sizeof(float);
  // ---- plain scratch (fully written before read) ----
  int* start   = (int*)alloc(NN + 1);
  int* cursor  = (int*)alloc(NN);
  uint2* csr   = (uint2*)alloc((size_t)ETOT * 2);
  u16* xl1 = (u16*)alloc((size_t)NN * 32);
  u16* xr1 = (u16*)alloc((size_t)NN * 32);
  u16* hp1 = (u16*)alloc((size_t)NN * 32);
  u16* agg = (u16*)alloc((size_t)NN * 32);
  // layer-2 overlays (source regions dead by then)
  u16* h1  = xr1;
  u16* xl2 = xl1;
  u16* xr2 = xl1 + (size_t)NN * 32;
  u16* hp2 = hp1;
  // total ws: ~33 MB

  hipMemsetAsync(d_ws, 0, zbytes, stream);
  k_detect<<<1, 256, 0, stream>>>((const unsigned*)x, (const unsigned*)skip1_W,
                                  (const unsigned*)eattr, flags);
  int eg = (ETOT + 255) / 256;
  k_histcol<<<eg, 256, 0, stream>>>(ei, eattr, flags, deg, mean_sums);
  k_scan<<<1, 256, 0, stream>>>(deg, start, cursor);
  k_buildcsr<<<eg, 256, 0, stream>>>(ei, cursor, csr);

  // ---- layer 1 ----
  {
    dim3 gm(125, 3);
    k_linear3_mfma<128, 64, 0><<<gm, 256, 0, stream>>>(x, flags, c1_Wl, c1_Wr, skip1_W,
                                                       c1_bl, c1_br, skip1_b,
                                                       xl1, xr1, hp1);
    dim3 g((NN + 31) / 32, 3);
    k_linear3<128, 64, 0><<<g, 256, 0, stream>>>(x, flags, c1_Wl, c1_Wr, skip1_W,
                                                 c1_bl, c1_br, skip1_b,
                                                 xl1, xr1, hp1, NN);
  }
  k_fused<2, 32><<<NN / 4, 256, 0, stream>>>(start, csr, eattr, flags, mean_sums,
                                             xl1, xr1, c1_We, c1_att, agg);
  k_bnred<64><<<256, 256, 0, stream>>>(agg, bnsum1, bnsq1, NN);
  k_bnapply<64><<<(NN * 64 + 255) / 256, 256, 0, stream>>>(agg, hp1, bnsum1, bnsq1,
                                                           bn1_g, bn1_b, flags, h1, NN);

  // ---- layer 2 ----
  {
    dim3 gm(125, 3);
    k_linear3_mfma<64, 32, 1><<<gm, 256, 0, stream>>>(h1, flags, c2_Wl, c2_Wr, skip2_W,
                                                      c2_bl, c2_br, skip2_b,
                                                      xl2, xr2, hp2);
    dim3 g((NN + 31) / 32, 3);
    k_linear3<64, 32, 1><<<g, 256, 0, stream>>>(h1, flags, c2_Wl, c2_Wr, skip2_W,
                                                c2_bl, c2_br, skip2_b,
                                                xl2, xr2, hp2, NN);
  }
  k_fused<1, 32><<<NN / 8, 256, 0, stream>>>(start, csr, eattr, flags, mean_sums,
                                             xl2, xr2, c2_We, c2_att, agg);
  k_bnred<32><<<256, 256, 0, stream>>>(agg, bnsum2, bnsq2, NN);
  k_poolall<<<(NN + 255) / 256, 256, 0, stream>>>(agg, hp2, bnsum2, bnsq2,
                                                  bn2_g, bn2_b, flags, batch,
                                                  pool_sum, pool_maxk, pool_cnt,
                                                  done_cnt, d_out);
}

// Round 10
// 802.155 us; speedup vs baseline: 1.1340x; 1.0045x over previous
//
#include <hip/hip_runtime.h>
#include <hip/hip_bf16.h>

#define NE 800000
#define NN 50000
#define NG 16
#define ETOT (NE + NN)

typedef unsigned short u16;
typedef __attribute__((ext_vector_type(8))) short short8;
typedef __attribute__((ext_vector_type(4))) float float4v;

__device__ __forceinline__ float b2f(u16 u) {
  return __uint_as_float(((unsigned)u) << 16);
}
__device__ __forceinline__ u16 f2b(float f) {
  __hip_bfloat16 b = __float2bfloat16(f);
  return *(u16*)&b;
}
__device__ __forceinline__ void cv8(uint4 v, float* o) {
  o[0] = __uint_as_float(v.x << 16);
  o[1] = __uint_as_float(v.x & 0xFFFF0000u);
  o[2] = __uint_as_float(v.y << 16);
  o[3] = __uint_as_float(v.y & 0xFFFF0000u);
  o[4] = __uint_as_float(v.z << 16);
  o[5] = __uint_as_float(v.z & 0xFFFF0000u);
  o[6] = __uint_as_float(v.w << 16);
  o[7] = __uint_as_float(v.w & 0xFFFF0000u);
}
__device__ __forceinline__ unsigned pk2(float a, float b) {
  return (unsigned)f2b(a) | ((unsigned)f2b(b) << 16);
}
__device__ __forceinline__ unsigned f2key(float f) {
  unsigned u = __float_as_uint(f);
  return (u & 0x80000000u) ? ~u : (u | 0x80000000u);
}
__device__ __forceinline__ float key2f(unsigned k) {
  unsigned u = (k & 0x80000000u) ? (k ^ 0x80000000u) : ~k;
  return __uint_as_float(u);
}

// ================= dtype detector (proven R4) =================
__device__ __forceinline__ int plaus(unsigned h) {
  unsigned eh = (h >> 7) & 0xFF;
  return (h == 0) || (eh >= 100 && eh <= 140);
}
__global__ __launch_bounds__(256) void k_detect(const unsigned* __restrict__ a,
                                                const unsigned* __restrict__ b,
                                                const unsigned* __restrict__ c,
                                                int* __restrict__ flags) {
  __shared__ int cnt[3];
  if (threadIdx.x < 3) cnt[threadIdx.x] = 0;
  __syncthreads();
  const unsigned* arr[3] = {a, b, c};
  for (int k = 0; k < 3; k++) {
    int ok = 0;
    for (int i = threadIdx.x; i < 4096; i += 256) {
      unsigned w = arr[k][i];
      ok += (plaus(w & 0xFFFFu) && plaus(w >> 16)) ? 1 : 0;
    }
    atomicAdd(&cnt[k], ok);
  }
  __syncthreads();
  if (threadIdx.x == 0) {
    int f0 = cnt[0] > 2048, f1 = cnt[1] > 2048, f2 = cnt[2] > 2048;
    flags[0] = f0;
    flags[1] = f1;
    flags[2] = f2;
    flags[3] = f0 && f1 && f2;
  }
}

// ============ merged: dst-degree histogram + edge_attr column sums ============
__global__ __launch_bounds__(256) void k_histcol(const int* __restrict__ ei,
                                                 const void* __restrict__ ea,
                                                 const int* __restrict__ flg,
                                                 int* __restrict__ deg,
                                                 float* __restrict__ sums) {
  int gt = blockIdx.x * 256 + threadIdx.x;
  if (gt < ETOT) {
    int dst = (gt < NE) ? ei[NE + gt] : gt - NE;
    atomicAdd(&deg[dst], 1);
  }
  bool eb = flg[2] != 0;
  int col = gt & 15;
  int row = gt >> 4;
  int rstride = (gridDim.x * 256) >> 4;
  float s = 0.f;
  if (eb) {
    const u16* p = (const u16*)ea;
    for (int e = row; e < NE; e += rstride) s += b2f(p[(size_t)e * 16 + col]);
  } else {
    const float* p = (const float*)ea;
    for (int e = row; e < NE; e += rstride) s += p[(size_t)e * 16 + col];
  }
  __shared__ float ls[256];
  ls[threadIdx.x] = s;
  __syncthreads();
  if (threadIdx.x < 16) {
    float t = 0.f;
    for (int i = threadIdx.x; i < 256; i += 16) t += ls[i];
    atomicAdd(&sums[threadIdx.x], t);
  }
}

__global__ __launch_bounds__(256) void k_scan(const int* __restrict__ deg,
                                              int* __restrict__ start,
                                              int* __restrict__ cursor) {
  __shared__ int ps[256];
  int t = threadIdx.x;
  const int CH = (NN + 255) / 256;
  int b0 = t * CH;
  int bend = min(b0 + CH, NN);
  int s = 0;
  for (int i = b0; i < bend; i++) s += deg[i];
  ps[t] = s;
  __syncthreads();
  for (int ofs = 1; ofs < 256; ofs <<= 1) {
    int v = (t >= ofs) ? ps[t - ofs] : 0;
    __syncthreads();
    ps[t] += v;
    __syncthreads();
  }
  int run = (t == 0) ? 0 : ps[t - 1];
  for (int i = b0; i < bend; i++) {
    start[i] = run;
    cursor[i] = run;
    run += deg[i];
  }
  if (t == 255) start[NN] = run;
}

// CSR build WITH edge-attr payload permuted into CSR order (fast path)
__global__ __launch_bounds__(256) void k_buildcsr_pay(
    const int* __restrict__ ei, const void* __restrict__ eattr,
    const int* __restrict__ flg, const float* __restrict__ mean_sums,
    int* __restrict__ cursor, int* __restrict__ csr_src,
    u16* __restrict__ ea_csr) {
  int e = blockIdx.x * 256 + threadIdx.x;
  if (e >= ETOT) return;
  bool eb = flg[2] != 0;
  int src, dst;
  if (e < NE) { src = ei[e]; dst = ei[NE + e]; } else { src = dst = e - NE; }
  uint4 r0, r1;
  if (e < NE) {
    if (eb) {
      const uint4* q = (const uint4*)((const u16*)eattr + (size_t)e * 16);
      r0 = q[0]; r1 = q[1];
    } else {
      const float* q = (const float*)eattr + (size_t)e * 16;
      u16 rec[16];
#pragma unroll
      for (int k = 0; k < 16; k++) rec[k] = f2b(q[k]);
      r0 = *(uint4*)rec; r1 = *(uint4*)(rec + 8);
    }
  } else {
    u16 rec[16];
#pragma unroll
    for (int k = 0; k < 16; k++) rec[k] = f2b(mean_sums[k] * (1.0f / NE));
    r0 = *(uint4*)rec; r1 = *(uint4*)(rec + 8);
  }
  int pos = atomicAdd(&cursor[dst], 1);
  csr_src[pos] = src;
  uint4* dstp = (uint4*)(ea_csr + (size_t)pos * 16);
  dstp[0] = r0;
  dstp[1] = r1;
}

// CSR build, eid-indirect variant (fallback when ws too small)
__global__ __launch_bounds__(256) void k_buildcsr(const int* __restrict__ ei,
                                                  int* __restrict__ cursor,
                                                  uint2* __restrict__ csr) {
  int e = blockIdx.x * 256 + threadIdx.x;
  if (e >= ETOT) return;
  int src, dst;
  if (e < NE) { src = ei[e]; dst = ei[NE + e]; } else { src = dst = e - NE; }
  int pos = atomicAdd(&cursor[dst], 1);
  uint2 r; r.x = (unsigned)src; r.y = (unsigned)e;
  csr[pos] = r;
}

// ==== merged 3x linear: MFMA fast path + VALU fallback in one kernel ====
template <int K, int N, int XMODE>
__global__ __launch_bounds__(256) void k_lin3(
    const void* __restrict__ xin, const int* __restrict__ flg,
    const void* W0, const void* W1, const void* W2,
    const void* b0, const void* b1, const void* b2,
    u16* __restrict__ o0, u16* __restrict__ o1, u16* __restrict__ o2, int M) {
  constexpr int TM = 32;
  constexpr size_t SMV = (size_t)(K * N + TM * (K + 1) + N) * 4;
  constexpr size_t SMM = (size_t)K * N * 2;
  __shared__ __align__(16) char smem[SMV > SMM ? SMV : SMM];
  bool wb = flg[1] != 0;
  bool xb = (XMODE == 1) ? true : (flg[0] != 0);
  const void* W = blockIdx.y == 0 ? W0 : (blockIdx.y == 1 ? W1 : W2);
  const void* bb = blockIdx.y == 0 ? b0 : (blockIdx.y == 1 ? b1 : b2);
  u16* out = blockIdx.y == 0 ? o0 : (blockIdx.y == 1 ? o1 : o2);

  if (wb && xb) {
    // ---------- MFMA path (grid.x = 125, 25 row-tiles per block) ----------
    constexpr int CT = N / 16;
    constexpr int WPC = 4 / CT;
    constexpr int KK = K / 32;
    const u16* Wp = (const u16*)W;
    const u16* bp = (const u16*)bb;
    const u16* xp = (const u16*)xin;
    u16* Wl = (u16*)smem;
    for (int i = threadIdx.x; i < K * N / 8; i += 256)
      *(uint4*)&Wl[i * 8] = ((const uint4*)Wp)[i];
    __syncthreads();
    int wave = threadIdx.x >> 6;
    int lane = threadIdx.x & 63;
    int col = lane & 15;
    int quad = lane >> 4;
    int ct = wave % CT;
    int rt_off = wave / CT;
    short8 bfrag[KK];
#pragma unroll
    for (int kk = 0; kk < KK; kk++) {
      short8 t;
#pragma unroll
      for (int j = 0; j < 8; j++)
        t[j] = (short)Wl[(kk * 32 + quad * 8 + j) * N + ct * 16 + col];
      bfrag[kk] = t;
    }
    float bias = b2f(bp[ct * 16 + col]);
    constexpr int RPB = 25;
    int rt0 = blockIdx.x * RPB;
    for (int i = rt_off; i < RPB; i += WPC) {
      int rt = rt0 + i;
      int row = rt * 16 + col;
      float4v acc = {0.f, 0.f, 0.f, 0.f};
#pragma unroll
      for (int kk = 0; kk < KK; kk++) {
        short8 afrag = *(const short8*)(xp + (size_t)row * K + kk * 32 + quad * 8);
        acc = __builtin_amdgcn_mfma_f32_16x16x32_bf16(afrag, bfrag[kk], acc, 0, 0, 0);
      }
#pragma unroll
      for (int r = 0; r < 4; r++) {
        int orow = rt * 16 + quad * 4 + r;
        out[(size_t)orow * N + ct * 16 + col] = f2b(acc[r] + bias);
      }
    }
  } else {
    // ---------- VALU fallback (loops row-chunks; perf secondary) ----------
    constexpr int CPT = (N >= 64) ? 8 : 4;
    constexpr int TCOLS = N / CPT;
    float* Wf = (float*)smem;
    float* xs = Wf + K * N;
    float* bfs = xs + TM * (K + 1);
    int tid = threadIdx.x;
    if (wb) {
      const u16* Wp = (const u16*)W;
      for (int i = tid; i < K * N / 8; i += 256) {
        float t[8];
        cv8(*(const uint4*)(Wp + i * 8), t);
#pragma unroll
        for (int q = 0; q < 8; q++) Wf[i * 8 + q] = t[q];
      }
    } else {
      const float* Wp = (const float*)W;
      for (int i = tid; i < K * N / 4; i += 256) {
        float4 v = *(const float4*)(Wp + i * 4);
        Wf[i * 4 + 0] = v.x; Wf[i * 4 + 1] = v.y;
        Wf[i * 4 + 2] = v.z; Wf[i * 4 + 3] = v.w;
      }
    }
    if (tid < N) bfs[tid] = wb ? b2f(((const u16*)bb)[tid]) : ((const float*)bb)[tid];
    int tc = tid % TCOLS, tr = tid / TCOLS;
    for (int r0 = blockIdx.x * TM; r0 < M; r0 += gridDim.x * TM) {
      __syncthreads();
      if (xb) {
        const u16* xp = (const u16*)xin;
        for (int i = tid; i < TM * K / 8; i += 256) {
          int lr = i / (K / 8), lc = (i % (K / 8)) * 8;
          int gr = r0 + lr;
          float t[8] = {0, 0, 0, 0, 0, 0, 0, 0};
          if (gr < M) cv8(*(const uint4*)(xp + (size_t)gr * K + lc), t);
#pragma unroll
          for (int q = 0; q < 8; q++) xs[lr * (K + 1) + lc + q] = t[q];
        }
      } else {
        const float* xp = (const float*)xin;
        for (int i = tid; i < TM * K / 4; i += 256) {
          int lr = i / (K / 4), lc = (i % (K / 4)) * 4;
          int gr = r0 + lr;
          float4 v = {0, 0, 0, 0};
          if (gr < M) v = *(const float4*)(xp + (size_t)gr * K + lc);
          xs[lr * (K + 1) + lc + 0] = v.x;
          xs[lr * (K + 1) + lc + 1] = v.y;
          xs[lr * (K + 1) + lc + 2] = v.z;
          xs[lr * (K + 1) + lc + 3] = v.w;
        }
      }
      __syncthreads();
      float acc[CPT];
#pragma unroll
      for (int c = 0; c < CPT; c++) acc[c] = bfs[tc * CPT + c];
#pragma unroll 4
      for (int k = 0; k < K; k++) {
        float xv = xs[tr * (K + 1) + k];
#pragma unroll
        for (int c = 0; c < CPT; c++) acc[c] += xv * Wf[k * N + tc * CPT + c];
      }
      int gr = r0 + tr;
      if (gr < M) {
        u16* op = out + (size_t)gr * N + tc * CPT;
        if constexpr (CPT == 8) {
          uint4 o;
          o.x = pk2(acc[0], acc[1]); o.y = pk2(acc[2], acc[3]);
          o.z = pk2(acc[4], acc[5]); o.w = pk2(acc[6], acc[7]);
          *(uint4*)op = o;
        } else {
          uint2 o;
          o.x = pk2(acc[0], acc[1]); o.y = pk2(acc[2], acc[3]);
          *(uint2*)op = o;
        }
      }
    }
  }
}

// ===== fused attention + softmax gather-reduce, sequential ea payload =====
template <int H, int C>
__global__ __launch_bounds__(256) void k_fusedp(
    const int* __restrict__ start, const int* __restrict__ csr_src,
    const u16* __restrict__ ea_csr, const int* __restrict__ flg,
    const u16* __restrict__ xl, const u16* __restrict__ xr,
    const void* We, const void* att, u16* __restrict__ agg) {
  constexpr int D = H * C;
  constexpr int NPW = 64 / D;
  bool wb = flg[1] != 0;
  int lane = threadIdx.x & 63;
  int ch = lane % D;
  float Wreg[16];
  if (wb) {
    const u16* Wp = (const u16*)We;
#pragma unroll
    for (int k = 0; k < 16; k++) Wreg[k] = b2f(Wp[k * D + ch]);
  } else {
    const float* Wp = (const float*)We;
#pragma unroll
    for (int k = 0; k < 16; k++) Wreg[k] = Wp[k * D + ch];
  }
  float attv = wb ? b2f(((const u16*)att)[ch]) : ((const float*)att)[ch];
  int wid = (blockIdx.x * 256 + threadIdx.x) >> 6;
  int node = wid * NPW + lane / D;
  if (node >= NN) return;
  int s0 = start[node], s1 = start[node + 1];
  int deg = s1 - s0;
  int last = s1 - 1;
  int degmax = deg;
  if constexpr (NPW == 2) degmax = max(deg, __shfl_xor(deg, 32, 64));
  float xrv = b2f(xr[(size_t)node * D + ch]);
  float ssum = 0.f, acc = 0.f;
  int src0 = csr_src[s0], src1 = csr_src[min(s0 + 1, last)];
  for (int i = 0; i < degmax; i += 2) {
    int p0 = min(s0 + i, last), p1 = min(s0 + i + 1, last);
    int c0 = src0, c1 = src1;
    src0 = csr_src[min(s0 + i + 2, last)];
    src1 = csr_src[min(s0 + i + 3, last)];
    bool a0 = i < deg, a1 = i + 1 < deg;
    float xlv0 = b2f(xl[(size_t)c0 * D + ch]);
    float xlv1 = b2f(xl[(size_t)c1 * D + ch]);
    float ea0[16], ea1[16];
    const uint4* qa = (const uint4*)(ea_csr + (size_t)p0 * 16);
    cv8(qa[0], ea0); cv8(qa[1], ea0 + 8);
    const uint4* qb = (const uint4*)(ea_csr + (size_t)p1 * 16);
    cv8(qb[0], ea1); cv8(qb[1], ea1 + 8);
    float ev0 = 0.f, ev1 = 0.f;
#pragma unroll
    for (int k = 0; k < 16; k++) {
      ev0 += ea0[k] * Wreg[k];
      ev1 += ea1[k] * Wreg[k];
    }
    float mv0 = xlv0 + xrv + ev0;
    float mv1 = xlv1 + xrv + ev1;
    mv0 = (mv0 > 0.f) ? mv0 : 0.2f * mv0;
    mv1 = (mv1 > 0.f) ? mv1 : 0.2f * mv1;
    float t0 = mv0 * attv, t1 = mv1 * attv;
#pragma unroll
    for (int mk = 1; mk <= 16; mk <<= 1) {
      t0 += __shfl_xor(t0, mk, 64);
      t1 += __shfl_xor(t1, mk, 64);
    }
    float ex0 = a0 ? __expf(t0) : 0.f;
    float ex1 = a1 ? __expf(t1) : 0.f;
    ssum += ex0 + ex1;
    acc += ex0 * xlv0 + ex1 * xlv1;
  }
  agg[(size_t)node * D + ch] = f2b(acc / (ssum + 1e-16f));
}

// ===== per-edge ev (eid-indirect fallback) =====
__device__ __forceinline__ float edot16(unsigned eid, const void* __restrict__ eattr,
                                        bool eb, const float* Wreg, float ev_self) {
  if (eid >= NE) return ev_self;
  float ea[16];
  if (eb) {
    const uint4* q = (const uint4*)((const u16*)eattr + (size_t)eid * 16);
    cv8(q[0], ea);
    cv8(q[1], ea + 8);
  } else {
    const float* q = (const float*)eattr + (size_t)eid * 16;
#pragma unroll
    for (int k = 0; k < 16; k++) ea[k] = q[k];
  }
  float ev = 0.f;
#pragma unroll
  for (int k = 0; k < 16; k++) ev += ea[k] * Wreg[k];
  return ev;
}

// ===== fused gather-reduce, eid-indirect (ws-too-small fallback) =====
template <int H, int C>
__global__ __launch_bounds__(256) void k_fusedg(
    const int* __restrict__ start, const uint2* __restrict__ csr,
    const void* __restrict__ eattr, const int* __restrict__ flg,
    const float* __restrict__ mean_sums,
    const u16* __restrict__ xl, const u16* __restrict__ xr,
    const void* We, const void* att, u16* __restrict__ agg) {
  constexpr int D = H * C;
  constexpr int NPW = 64 / D;
  bool wb = flg[1] != 0;
  bool eb = flg[2] != 0;
  int lane = threadIdx.x & 63;
  int ch = lane % D;
  float Wreg[16];
  if (wb) {
    const u16* Wp = (const u16*)We;
#pragma unroll
    for (int k = 0; k < 16; k++) Wreg[k] = b2f(Wp[k * D + ch]);
  } else {
    const float* Wp = (const float*)We;
#pragma unroll
    for (int k = 0; k < 16; k++) Wreg[k] = Wp[k * D + ch];
  }
  float attv = wb ? b2f(((const u16*)att)[ch]) : ((const float*)att)[ch];
  float ev_self = 0.f;
#pragma unroll
  for (int k = 0; k < 16; k++) ev_self += mean_sums[k] * (1.0f / NE) * Wreg[k];
  int wid = (blockIdx.x * 256 + threadIdx.x) >> 6;
  int node = wid * NPW + lane / D;
  if (node >= NN) return;
  int s0 = start[node], s1 = start[node + 1];
  int deg = s1 - s0;
  int last = s1 - 1;
  int degmax = deg;
  if constexpr (NPW == 2) degmax = max(deg, __shfl_xor(deg, 32, 64));
  float xrv = b2f(xr[(size_t)node * D + ch]);
  float ssum = 0.f, acc = 0.f;
  uint2 nA = csr[s0];
  uint2 nB = csr[min(s0 + 1, last)];
  for (int i = 0; i < degmax; i += 2) {
    uint2 cr0 = nA, cr1 = nB;
    nA = csr[min(s0 + i + 2, last)];
    nB = csr[min(s0 + i + 3, last)];
    bool a0 = i < deg, a1 = i + 1 < deg;
    float xlv0 = b2f(xl[(size_t)cr0.x * D + ch]);
    float xlv1 = b2f(xl[(size_t)cr1.x * D + ch]);
    float ev0 = edot16(cr0.y, eattr, eb, Wreg, ev_self);
    float ev1 = edot16(cr1.y, eattr, eb, Wreg, ev_self);
    float mv0 = xlv0 + xrv + ev0;
    float mv1 = xlv1 + xrv + ev1;
    mv0 = (mv0 > 0.f) ? mv0 : 0.2f * mv0;
    mv1 = (mv1 > 0.f) ? mv1 : 0.2f * mv1;
    float t0 = mv0 * attv, t1 = mv1 * attv;
#pragma unroll
    for (int mk = 1; mk <= 16; mk <<= 1) {
      t0 += __shfl_xor(t0, mk, 64);
      t1 += __shfl_xor(t1, mk, 64);
    }
    float ex0 = a0 ? __expf(t0) : 0.f;
    float ex1 = a1 ? __expf(t1) : 0.f;
    ssum += ex0 + ex1;
    acc += ex0 * xlv0 + ex1 * xlv1;
  }
  agg[(size_t)node * D + ch] = f2b(acc / (ssum + 1e-16f));
}

// ================= batch-norm reduce (agg bf16) =================
template <int D>
__global__ __launch_bounds__(256) void k_bnred(const u16* __restrict__ v,
                                               float* __restrict__ sum,
                                               float* __restrict__ sq, int M) {
  constexpr int RB = 256 / D;
  int tid = threadIdx.x;
  int c = tid % D;
  int rg = tid / D;
  float s = 0.f, q = 0.f;
  for (int r = blockIdx.x * RB + rg; r < M; r += gridDim.x * RB) {
    float x = b2f(v[(size_t)r * D + c]);
    s += x;
    q += x * x;
  }
  __shared__ float ls[256], lq[256];
  ls[tid] = s; lq[tid] = q;
  __syncthreads();
  if (tid < D) {
    float ts = 0.f, tq = 0.f;
    for (int i = tid; i < 256; i += D) { ts += ls[i]; tq += lq[i]; }
    atomicAdd(&sum[tid], ts);
    atomicAdd(&sq[tid], tq);
  }
}

// ================= batch-norm apply + skip + ELU (layer 1) =================
template <int D>
__global__ __launch_bounds__(256) void k_bnapply(const u16* __restrict__ agg,
                                                 const u16* __restrict__ hp,
                                                 const float* __restrict__ sum,
                                                 const float* __restrict__ sq,
                                                 const void* g, const void* b,
                                                 const int* __restrict__ flg,
                                                 u16* __restrict__ out, int M) {
  bool wb = flg[1] != 0;
  int idx = blockIdx.x * 256 + threadIdx.x;
  if (idx >= M * D) return;
  int c = idx & (D - 1);
  float gc = wb ? b2f(((const u16*)g)[c]) : ((const float*)g)[c];
  float bc = wb ? b2f(((const u16*)b)[c]) : ((const float*)b)[c];
  float mu = sum[c] * (1.f / M);
  float var = fmaxf(sq[c] * (1.f / M) - mu * mu, 0.f);
  float sc = rsqrtf(var + 1e-5f) * gc;
  float v = (b2f(agg[idx]) - mu) * sc + bc + b2f(hp[idx]);
  v = v > 0.f ? v : expm1f(v);
  out[idx] = f2b(v);
}

// ==== fused: BN2-apply + ELU + graph pool + (last block) finalize ====
__global__ __launch_bounds__(256) void k_poolall(
    const u16* __restrict__ agg2, const u16* __restrict__ hp2,
    const float* __restrict__ sum, const float* __restrict__ sq,
    const void* g, const void* b, const int* __restrict__ flg,
    const int* __restrict__ batch,
    float* __restrict__ pool_sum, unsigned* __restrict__ pool_maxk,
    float* __restrict__ pool_cnt, int* __restrict__ done_cnt,
    void* __restrict__ out) {
  bool wb = flg[1] != 0;
  int c = threadIdx.x & 31;
  int rg = threadIdx.x >> 5;
  float gc = wb ? b2f(((const u16*)g)[c]) : ((const float*)g)[c];
  float bc = wb ? b2f(((const u16*)b)[c]) : ((const float*)b)[c];
  float mu = sum[c] * (1.f / NN);
  float var = fmaxf(sq[c] * (1.f / NN) - mu * mu, 0.f);
  float scl = rsqrtf(var + 1e-5f) * gc;
  float sh = bc - mu * scl;

  const int NPB = 256;
  int n0 = blockIdx.x * NPB;
  int nend = min(n0 + NPB, NN);
  int cur = -1;
  float s = 0.f, mx = 0.f;
  int cnt = 0;
  for (int n = n0 + rg; n < nend; n += 8) {
    int gi = batch[n];
    float v = b2f(agg2[(size_t)n * 32 + c]) * scl + sh + b2f(hp2[(size_t)n * 32 + c]);
    v = v > 0.f ? v : expm1f(v);
    if (gi != cur) {
      if (cur >= 0) {
        atomicAdd(&pool_sum[cur * 32 + c], s);
        atomicMax(&pool_maxk[cur * 32 + c], f2key(mx));
        if (c == 0) atomicAdd(&pool_cnt[cur], (float)cnt);
      }
      cur = gi; s = 0.f; mx = -INFINITY; cnt = 0;
    }
    s += v;
    mx = fmaxf(mx, v);
    cnt++;
  }
  if (cur >= 0) {
    atomicAdd(&pool_sum[cur * 32 + c], s);
    atomicMax(&pool_maxk[cur * 32 + c], f2key(mx));
    if (c == 0) atomicAdd(&pool_cnt[cur], (float)cnt);
  }
  __threadfence();
  __syncthreads();
  __shared__ int lastblk;
  if (threadIdx.x == 0) lastblk = (atomicAdd(done_cnt, 1) == (int)gridDim.x - 1);
  __syncthreads();
  if (!lastblk) return;
  bool ob = flg[3] != 0;
  for (int idx = threadIdx.x; idx < NG * 64; idx += 256) {
    int gi = idx / 64, cc = idx % 64;
    float cntv = atomicAdd(&pool_cnt[gi], 0.f);
    float val;
    if (cc < 32) val = atomicAdd(&pool_sum[gi * 32 + cc], 0.f) / fmaxf(cntv, 1.f);
    else {
      unsigned k = atomicMax(&pool_maxk[gi * 32 + (cc - 32)], 0u);
      val = cntv > 0.f ? key2f(k) : 0.f;
    }
    if (ob) ((u16*)out)[idx] = f2b(val);
    else ((float*)out)[idx] = val;
  }
}

extern "C" void kernel_launch(void* const* d_in, const int* in_sizes, int n_in,
                              void* d_out, int out_size, void* d_ws, size_t ws_size,
                              hipStream_t stream) {
  (void)in_sizes; (void)n_in; (void)out_size;
  const void* x     = d_in[0];
  const int*  ei    = (const int*)d_in[1];
  const void* eattr = d_in[2];
  const int*  batch = (const int*)d_in[3];
  const void* skip1_W = d_in[4];
  const void* skip1_b = d_in[5];
  const void* c1_Wl = d_in[6];
  const void* c1_bl = d_in[7];
  const void* c1_Wr = d_in[8];
  const void* c1_br = d_in[9];
  const void* c1_We = d_in[10];
  const void* c1_att = d_in[11];
  const void* bn1_g = d_in[13];
  const void* bn1_b = d_in[14];
  const void* skip2_W = d_in[15];
  const void* skip2_b = d_in[16];
  const void* c2_Wl = d_in[17];
  const void* c2_bl = d_in[18];
  const void* c2_Wr = d_in[19];
  const void* c2_br = d_in[20];
  const void* c2_We = d_in[21];
  const void* c2_att = d_in[22];
  const void* bn2_g = d_in[24];
  const void* bn2_b = d_in[25];

  float* ws = (float*)d_ws;
  size_t off = 0;
  auto alloc = [&](size_t nfl) {
    float* p = ws + off;
    off += (nfl + 15) & ~(size_t)15;
    return p;
  };
  // ---- zero-initialized region (memset) ----
  int*   flags      = (int*)alloc(16);
  float* mean_sums  = alloc(16);
  int*   deg        = (int*)alloc(NN);
  float* bnsum1     = alloc(64);
  float* bnsq1      = alloc(64);
  float* bnsum2     = alloc(32);
  float* bnsq2      = alloc(32);
  float* pool_cnt   = alloc(NG);
  float* pool_sum   = alloc(NG * 32);
  unsigned* pool_maxk = (unsigned*)alloc(NG * 32);
  int*   done_cnt   = (int*)alloc(16);
  size_t zbytes = off * sizeof(float);
  size_t zoff = off;

  // ---- try FAST layout (ea payload permuted into CSR order, ~57 MB) ----
  int* start   = (int*)alloc(NN + 1);
  int* cursor  = (int*)alloc(NN);
  int* csr_src = (int*)alloc(ETOT);
  u16* ea_csr  = (u16*)alloc((size_t)ETOT * 8);   // ETOT*16 bf16
  u16* xl1 = (u16*)alloc((size_t)NN * 32);
  u16* xr1 = (u16*)alloc((size_t)NN * 32);
  u16* hp1 = (u16*)alloc((size_t)NN * 32);
  u16* agg = (u16*)alloc((size_t)NN * 32);
  uint2* csr = nullptr;
  bool fast = (off * sizeof(float)) <= ws_size;
  if (!fast) {
    // ---- FALLBACK layout (~33 MB, eid-indirect eattr) ----
    off = zoff;
    start   = (int*)alloc(NN + 1);
    cursor  = (int*)alloc(NN);
    csr     = (uint2*)alloc((size_t)ETOT * 2);
    xl1 = (u16*)alloc((size_t)NN * 32);
    xr1 = (u16*)alloc((size_t)NN * 32);
    hp1 = (u16*)alloc((size_t)NN * 32);
    agg = (u16*)alloc((size_t)NN * 32);
  }
  // layer-2 overlays (source regions dead by then)
  u16* h1  = xr1;
  u16* xl2 = xl1;
  u16* xr2 = xl1 + (size_t)NN * 32;
  u16* hp2 = hp1;

  hipMemsetAsync(d_ws, 0, zbytes, stream);
  k_detect<<<1, 256, 0, stream>>>((const unsigned*)x, (const unsigned*)skip1_W,
                                  (const unsigned*)eattr, flags);
  int eg = (ETOT + 255) / 256;
  k_histcol<<<eg, 256, 0, stream>>>(ei, eattr, flags, deg, mean_sums);
  k_scan<<<1, 256, 0, stream>>>(deg, start, cursor);
  if (fast) {
    k_buildcsr_pay<<<eg, 256, 0, stream>>>(ei, eattr, flags, mean_sums,
                                           cursor, csr_src, ea_csr);
  } else {
    k_buildcsr<<<eg, 256, 0, stream>>>(ei, cursor, csr);
  }

  // ---- layer 1 ----
  {
    dim3 g(125, 3);
    k_lin3<128, 64, 0><<<g, 256, 0, stream>>>(x, flags, c1_Wl, c1_Wr, skip1_W,
                                              c1_bl, c1_br, skip1_b,
                                              xl1, xr1, hp1, NN);
  }
  if (fast) {
    k_fusedp<2, 32><<<NN / 4, 256, 0, stream>>>(start, csr_src, ea_csr, flags,
                                                xl1, xr1, c1_We, c1_att, agg);
  } else {
    k_fusedg<2, 32><<<NN / 4, 256, 0, stream>>>(start, csr, eattr, flags, mean_sums,
                                                xl1, xr1, c1_We, c1_att, agg);
  }
  k_bnred<64><<<256, 256, 0, stream>>>(agg, bnsum1, bnsq1, NN);
  k_bnapply<64><<<(NN * 64 + 255) / 256, 256, 0, stream>>>(agg, hp1, bnsum1, bnsq1,
                                                           bn1_g, bn1_b, flags, h1, NN);

  // ---- layer 2 ----
  {
    dim3 g(125, 3);
    k_lin3<64, 32, 1><<<g, 256, 0, stream>>>(h1, flags, c2_Wl, c2_Wr, skip2_W,
                                             c2_bl, c2_br, skip2_b,
                                             xl2, xr2, hp2, NN);
  }
  if (fast) {
    k_fusedp<1, 32><<<NN / 8, 256, 0, stream>>>(start, csr_src, ea_csr, flags,
                                                xl2, xr2, c2_We, c2_att, agg);
  } else {
    k_fusedg<1, 32><<<NN / 8, 256, 0, stream>>>(start, csr, eattr, flags, mean_sums,
                                                xl2, xr2, c2_We, c2_att, agg);
  }
  k_bnred<32><<<256, 256, 0, stream>>>(agg, bnsum2, bnsq2, NN);
  k_poolall<<<(NN + 255) / 256, 256, 0, stream>>>(agg, hp2, bnsum2, bnsq2,
                                                  bn2_g, bn2_b, flags, batch,
                                                  pool_sum, pool_maxk, pool_cnt,
                                                  done_cnt, d_out);
}